// Round 1
// baseline (1000.394 us; speedup 1.0000x reference)
//
#include <hip/hip_runtime.h>
#include <hip/hip_bf16.h>

#define IN_F 108   // concat(x[107], votes[1])
#define XD   107
#define HID  128
#define OUTD 64

__device__ inline void atomicMaxF(float* addr, float val) {
    if (val >= 0.f) atomicMax((int*)addr, __float_as_int(val));
    else            atomicMin((unsigned int*)addr, __float_as_uint(val));
}

// out init to -inf
__global__ void init_out_kernel(float* out, int n) {
    int i = blockIdx.x * 256 + threadIdx.x;
    if (i < n) out[i] = -__builtin_inff();
}

// Layer-1 scatter: agg1[dst][f] += h0[src][f]; deg[dst] += 1 (lane f==0)
__global__ void scatter1_kernel(const float* __restrict__ x, const float* __restrict__ votes,
                                const int* __restrict__ src, const int* __restrict__ dst,
                                float* __restrict__ agg1, float* __restrict__ deg, int E) {
    long long idx = (long long)blockIdx.x * 256 + threadIdx.x;
    int e = (int)(idx >> 7);
    int f = (int)(idx & 127);
    if (e >= E) return;
    int s = src[e];
    int d = dst[e];
    if (f == 0) unsafeAtomicAdd(&deg[d], 1.0f);
    if (f < IN_F) {
        float v = (f < XD) ? x[(long long)s * XD + f] : votes[s];
        unsafeAtomicAdd(&agg1[(long long)d * IN_F + f], v);
    }
}

// Layer-2 scatter: agg2[dst][f] += h1[src][f], f in [0,128)
__global__ void scatter2_kernel(const float* __restrict__ h1,
                                const int* __restrict__ src, const int* __restrict__ dst,
                                float* __restrict__ agg2, int E) {
    long long idx = (long long)blockIdx.x * 256 + threadIdx.x;
    int e = (int)(idx >> 7);
    int f = (int)(idx & 127);
    if (e >= E) return;
    int s = src[e];
    int d = dst[e];
    unsafeAtomicAdd(&agg2[(long long)d * HID + f], h1[(long long)s * HID + f]);
}

// h1[n][j] = relu( (agg1[n]/max(deg,1)) @ W1l + b1 + h0[n] @ W1r )
#define NP1 8
__global__ __launch_bounds__(128) void gemm1_kernel(
        const float* __restrict__ x, const float* __restrict__ votes,
        const float* __restrict__ agg1, const float* __restrict__ deg,
        const float* __restrict__ W1l, const float* __restrict__ b1,
        const float* __restrict__ W1r, float* __restrict__ h1, int N) {
    __shared__ float sh_h0[NP1][IN_F];
    __shared__ float sh_ag[NP1][IN_F];
    int j = threadIdx.x;
    int n0 = blockIdx.x * NP1;
    for (int i = threadIdx.x; i < NP1 * IN_F; i += 128) {
        int m = i / IN_F, k = i % IN_F;
        int n = n0 + m;
        float h0v = 0.f, agv = 0.f;
        if (n < N) {
            h0v = (k < XD) ? x[(long long)n * XD + k] : votes[n];
            agv = agg1[(long long)n * IN_F + k] / fmaxf(deg[n], 1.0f);
        }
        sh_h0[m][k] = h0v;
        sh_ag[m][k] = agv;
    }
    __syncthreads();
    float acc[NP1];
#pragma unroll
    for (int m = 0; m < NP1; ++m) acc[m] = 0.f;
    for (int k = 0; k < IN_F; ++k) {
        float wl = W1l[k * HID + j];
        float wr = W1r[k * HID + j];
#pragma unroll
        for (int m = 0; m < NP1; ++m)
            acc[m] += sh_ag[m][k] * wl + sh_h0[m][k] * wr;
    }
    float bj = b1[j];
#pragma unroll
    for (int m = 0; m < NP1; ++m) {
        int n = n0 + m;
        if (n < N) h1[(long long)n * HID + j] = fmaxf(acc[m] + bj, 0.f);
    }
}

// h2[n][j] = (agg2[n]/max(deg,1)) @ W2l + b2 + h1[n] @ W2r
#define NP2 8
__global__ __launch_bounds__(64) void gemm2_kernel(
        const float* __restrict__ h1, const float* __restrict__ agg2,
        const float* __restrict__ deg,
        const float* __restrict__ W2l, const float* __restrict__ b2,
        const float* __restrict__ W2r, float* __restrict__ h2, int N) {
    __shared__ float sh_h[NP2][HID];
    __shared__ float sh_a[NP2][HID];
    int j = threadIdx.x;  // 0..63
    int n0 = blockIdx.x * NP2;
    for (int i = threadIdx.x; i < NP2 * HID; i += 64) {
        int m = i >> 7, k = i & 127;
        int n = n0 + m;
        float hv = 0.f, av = 0.f;
        if (n < N) {
            hv = h1[(long long)n * HID + k];
            av = agg2[(long long)n * HID + k] / fmaxf(deg[n], 1.0f);
        }
        sh_h[m][k] = hv;
        sh_a[m][k] = av;
    }
    __syncthreads();
    float acc[NP2];
#pragma unroll
    for (int m = 0; m < NP2; ++m) acc[m] = 0.f;
    for (int k = 0; k < HID; ++k) {
        float wl = W2l[k * OUTD + j];
        float wr = W2r[k * OUTD + j];
#pragma unroll
        for (int m = 0; m < NP2; ++m)
            acc[m] += sh_a[m][k] * wl + sh_h[m][k] * wr;
    }
    float bj = b2[j];
#pragma unroll
    for (int m = 0; m < NP2; ++m) {
        int n = n0 + m;
        if (n < N) h2[(long long)n * OUTD + j] = acc[m] + bj;
    }
}

// out[g][j] = max over nodes n with batch[n]==g of h2[n][j]
__global__ void segmax_kernel(const float* __restrict__ h2, const int* __restrict__ batch,
                              float* __restrict__ out, int N) {
    long long idx = (long long)blockIdx.x * 256 + threadIdx.x;
    if (idx >= (long long)N * OUTD) return;
    int n = (int)(idx >> 6);
    int j = (int)(idx & 63);
    float v = h2[idx];
    int g = batch[n];
    atomicMaxF(&out[g * OUTD + j], v);
}

extern "C" void kernel_launch(void* const* d_in, const int* in_sizes, int n_in,
                              void* d_out, int out_size, void* d_ws, size_t ws_size,
                              hipStream_t stream) {
    const float* x     = (const float*)d_in[0];
    const float* votes = (const float*)d_in[1];
    const int*   eidx  = (const int*)d_in[2];   // [2, E]
    const int*   batch = (const int*)d_in[3];
    const float* W1l   = (const float*)d_in[4];
    const float* b1    = (const float*)d_in[5];
    const float* W1r   = (const float*)d_in[6];
    const float* W2l   = (const float*)d_in[7];
    const float* b2    = (const float*)d_in[8];
    const float* W2r   = (const float*)d_in[9];
    float* out = (float*)d_out;

    const int N = in_sizes[1];          // 50000
    const int E = in_sizes[2] / 2;      // 800000

    const int* src = eidx;
    const int* dst = eidx + E;

    // workspace layout (floats)
    float* ws = (float*)d_ws;
    float* deg  = ws;                       // N
    float* agg1 = deg + N;                  // N*108
    float* agg2 = agg1 + (long long)N * IN_F;   // N*128
    float* h1   = agg2 + (long long)N * HID;    // N*128
    float* h2   = h1 + (long long)N * HID;      // N*64

    // zero deg + agg1 + agg2 (contiguous): (1 + 108 + 128) * N floats
    size_t zero_bytes = (size_t)(1 + IN_F + HID) * N * sizeof(float);
    hipMemsetAsync(d_ws, 0, zero_bytes, stream);

    init_out_kernel<<<(out_size + 255) / 256, 256, 0, stream>>>(out, out_size);

    {
        long long tot = (long long)E * 128;
        int blocks = (int)((tot + 255) / 256);
        scatter1_kernel<<<blocks, 256, 0, stream>>>(x, votes, src, dst, agg1, deg, E);
    }
    gemm1_kernel<<<(N + NP1 - 1) / NP1, 128, 0, stream>>>(x, votes, agg1, deg, W1l, b1, W1r, h1, N);
    {
        long long tot = (long long)E * 128;
        int blocks = (int)((tot + 255) / 256);
        scatter2_kernel<<<blocks, 256, 0, stream>>>(h1, src, dst, agg2, E);
    }
    gemm2_kernel<<<(N + NP2 - 1) / NP2, 64, 0, stream>>>(h1, agg2, deg, W2l, b2, W2r, h2, N);
    {
        long long tot = (long long)N * OUTD;
        int blocks = (int)((tot + 255) / 256);
        segmax_kernel<<<blocks, 256, 0, stream>>>(h2, batch, out, N);
    }
}

// Round 2
// 587.193 us; speedup vs baseline: 1.7037x; 1.7037x over previous
//
#include <hip/hip_runtime.h>
#include <hip/hip_bf16.h>

#define IN_F 108   // concat(x[107], votes[1])
#define XD   107
#define HID  128
#define OUTD 64

__device__ inline void atomicMaxF(float* addr, float val) {
    if (val >= 0.f) atomicMax((int*)addr, __float_as_int(val));
    else            atomicMin((unsigned int*)addr, __float_as_uint(val));
}

// out init to -inf
__global__ void init_out_kernel(float* out, int n) {
    int i = blockIdx.x * 256 + threadIdx.x;
    if (i < n) out[i] = -__builtin_inff();
}

// ---- CSR build ----------------------------------------------------------
__global__ void hist_kernel(const int* __restrict__ dst, int* __restrict__ deg_i, int E) {
    int e = blockIdx.x * 256 + threadIdx.x;
    if (e < E) atomicAdd(&deg_i[dst[e]], 1);
}

// single-block exclusive scan of deg_i -> row_start[N+1], cursor[N]
__global__ __launch_bounds__(1024) void scan_kernel(const int* __restrict__ deg_i,
                                                    int* __restrict__ row_start,
                                                    int* __restrict__ cursor, int N) {
    __shared__ int s[1024];
    int tid = threadIdx.x;
    int per = (N + 1023) / 1024;
    int begin = tid * per;
    int end = min(begin + per, N);
    int sum = 0;
    for (int i = begin; i < end; ++i) sum += deg_i[i];
    s[tid] = sum;
    __syncthreads();
    // Hillis-Steele inclusive scan
    for (int d = 1; d < 1024; d <<= 1) {
        int t = (tid >= d) ? s[tid - d] : 0;
        __syncthreads();
        s[tid] += t;
        __syncthreads();
    }
    int off = s[tid] - sum;   // exclusive prefix
    for (int i = begin; i < end; ++i) {
        row_start[i] = off;
        cursor[i] = off;
        off += deg_i[i];
    }
    if (tid == 1023) row_start[N] = s[1023];
}

__global__ void place_kernel(const int* __restrict__ src, const int* __restrict__ dst,
                             int* __restrict__ cursor, int* __restrict__ sorted_src, int E) {
    int e = blockIdx.x * 256 + threadIdx.x;
    if (e >= E) return;
    int pos = atomicAdd(&cursor[dst[e]], 1);
    sorted_src[pos] = src[e];
}

// ---- gather mean-aggregation -------------------------------------------
// one wave (64 lanes) per node; agg1 = mean of h0[src] rows (pre-divided)
__global__ __launch_bounds__(256) void gather1_kernel(
        const float* __restrict__ x, const float* __restrict__ votes,
        const int* __restrict__ row_start, const int* __restrict__ sorted_src,
        float* __restrict__ agg1, int N) {
    int wave = (blockIdx.x * 256 + threadIdx.x) >> 6;
    int lane = threadIdx.x & 63;
    if (wave >= N) return;
    int rs = row_start[wave], re = row_start[wave + 1];
    float a0 = 0.f, a1 = 0.f;
    for (int k0 = rs; k0 < re; k0 += 64) {
        int cnt = min(64, re - k0);
        int sl = sorted_src[k0 + min(lane, cnt - 1)];
        for (int t = 0; t < cnt; ++t) {
            int s = __shfl(sl, t);
            a0 += x[(long long)s * XD + lane];                 // f = lane in [0,63] < 107
            if (lane < IN_F - 64) {                            // f = lane+64 in [64,107]
                a1 += (lane + 64 < XD) ? x[(long long)s * XD + lane + 64] : votes[s];
            }
        }
    }
    float inv = 1.f / fmaxf((float)(re - rs), 1.f);
    agg1[(long long)wave * IN_F + lane] = a0 * inv;
    if (lane < IN_F - 64) agg1[(long long)wave * IN_F + lane + 64] = a1 * inv;
}

__global__ __launch_bounds__(256) void gather2_kernel(
        const float* __restrict__ h1,
        const int* __restrict__ row_start, const int* __restrict__ sorted_src,
        float* __restrict__ agg2, int N) {
    int wave = (blockIdx.x * 256 + threadIdx.x) >> 6;
    int lane = threadIdx.x & 63;
    if (wave >= N) return;
    int rs = row_start[wave], re = row_start[wave + 1];
    float a0 = 0.f, a1 = 0.f;
    for (int k0 = rs; k0 < re; k0 += 64) {
        int cnt = min(64, re - k0);
        int sl = sorted_src[k0 + min(lane, cnt - 1)];
        for (int t = 0; t < cnt; ++t) {
            int s = __shfl(sl, t);
            long long base = (long long)s * HID;
            a0 += h1[base + lane];
            a1 += h1[base + lane + 64];
        }
    }
    float inv = 1.f / fmaxf((float)(re - rs), 1.f);
    agg2[(long long)wave * HID + lane] = a0 * inv;
    agg2[(long long)wave * HID + lane + 64] = a1 * inv;
}

// ---- dense layers -------------------------------------------------------
// h1[n][j] = relu( agg1[n] @ W1l + b1 + h0[n] @ W1r )    (agg1 pre-divided)
#define NP1 8
__global__ __launch_bounds__(128) void gemm1_kernel(
        const float* __restrict__ x, const float* __restrict__ votes,
        const float* __restrict__ agg1,
        const float* __restrict__ W1l, const float* __restrict__ b1,
        const float* __restrict__ W1r, float* __restrict__ h1, int N) {
    __shared__ float sh_h0[NP1][IN_F];
    __shared__ float sh_ag[NP1][IN_F];
    int j = threadIdx.x;
    int n0 = blockIdx.x * NP1;
    for (int i = threadIdx.x; i < NP1 * IN_F; i += 128) {
        int m = i / IN_F, k = i % IN_F;
        int n = n0 + m;
        float h0v = 0.f, agv = 0.f;
        if (n < N) {
            h0v = (k < XD) ? x[(long long)n * XD + k] : votes[n];
            agv = agg1[(long long)n * IN_F + k];
        }
        sh_h0[m][k] = h0v;
        sh_ag[m][k] = agv;
    }
    __syncthreads();
    float acc[NP1];
#pragma unroll
    for (int m = 0; m < NP1; ++m) acc[m] = 0.f;
    for (int k = 0; k < IN_F; ++k) {
        float wl = W1l[k * HID + j];
        float wr = W1r[k * HID + j];
#pragma unroll
        for (int m = 0; m < NP1; ++m)
            acc[m] += sh_ag[m][k] * wl + sh_h0[m][k] * wr;
    }
    float bj = b1[j];
#pragma unroll
    for (int m = 0; m < NP1; ++m) {
        int n = n0 + m;
        if (n < N) h1[(long long)n * HID + j] = fmaxf(acc[m] + bj, 0.f);
    }
}

// h2[n][j] = agg2[n] @ W2l + b2 + h1[n] @ W2r        (agg2 pre-divided)
#define NP2 8
__global__ __launch_bounds__(64) void gemm2_kernel(
        const float* __restrict__ h1, const float* __restrict__ agg2,
        const float* __restrict__ W2l, const float* __restrict__ b2,
        const float* __restrict__ W2r, float* __restrict__ h2, int N) {
    __shared__ float sh_h[NP2][HID];
    __shared__ float sh_a[NP2][HID];
    int j = threadIdx.x;  // 0..63
    int n0 = blockIdx.x * NP2;
    for (int i = threadIdx.x; i < NP2 * HID; i += 64) {
        int m = i >> 7, k = i & 127;
        int n = n0 + m;
        float hv = 0.f, av = 0.f;
        if (n < N) {
            hv = h1[(long long)n * HID + k];
            av = agg2[(long long)n * HID + k];
        }
        sh_h[m][k] = hv;
        sh_a[m][k] = av;
    }
    __syncthreads();
    float acc[NP2];
#pragma unroll
    for (int m = 0; m < NP2; ++m) acc[m] = 0.f;
    for (int k = 0; k < HID; ++k) {
        float wl = W2l[k * OUTD + j];
        float wr = W2r[k * OUTD + j];
#pragma unroll
        for (int m = 0; m < NP2; ++m)
            acc[m] += sh_a[m][k] * wl + sh_h[m][k] * wr;
    }
    float bj = b2[j];
#pragma unroll
    for (int m = 0; m < NP2; ++m) {
        int n = n0 + m;
        if (n < N) h2[(long long)n * OUTD + j] = acc[m] + bj;
    }
}

// out[g][j] = max over nodes n with batch[n]==g of h2[n][j]
__global__ void segmax_kernel(const float* __restrict__ h2, const int* __restrict__ batch,
                              float* __restrict__ out, int N) {
    long long idx = (long long)blockIdx.x * 256 + threadIdx.x;
    if (idx >= (long long)N * OUTD) return;
    int n = (int)(idx >> 6);
    int j = (int)(idx & 63);
    float v = h2[idx];
    int g = batch[n];
    atomicMaxF(&out[g * OUTD + j], v);
}

extern "C" void kernel_launch(void* const* d_in, const int* in_sizes, int n_in,
                              void* d_out, int out_size, void* d_ws, size_t ws_size,
                              hipStream_t stream) {
    const float* x     = (const float*)d_in[0];
    const float* votes = (const float*)d_in[1];
    const int*   eidx  = (const int*)d_in[2];   // [2, E]
    const int*   batch = (const int*)d_in[3];
    const float* W1l   = (const float*)d_in[4];
    const float* b1    = (const float*)d_in[5];
    const float* W1r   = (const float*)d_in[6];
    const float* W2l   = (const float*)d_in[7];
    const float* b2    = (const float*)d_in[8];
    const float* W2r   = (const float*)d_in[9];
    float* out = (float*)d_out;

    const int N = in_sizes[1];          // 50000
    const int E = in_sizes[2] / 2;      // 800000

    const int* src = eidx;
    const int* dst = eidx + E;

    // workspace layout
    char* ws = (char*)d_ws;
    int* deg_i      = (int*)ws;                     ws += (size_t)N * 4;
    int* row_start  = (int*)ws;                     ws += (size_t)(N + 1) * 4;
    int* cursor     = (int*)ws;                     ws += (size_t)N * 4;
    int* sorted_src = (int*)ws;                     ws += (size_t)E * 4;
    float* agg1 = (float*)ws;                       ws += (size_t)N * IN_F * 4;
    float* agg2 = (float*)ws;                       ws += (size_t)N * HID * 4;
    float* h1   = (float*)ws;                       ws += (size_t)N * HID * 4;
    float* h2   = (float*)ws;

    // zero only the histogram
    hipMemsetAsync(deg_i, 0, (size_t)N * 4, stream);
    init_out_kernel<<<(out_size + 255) / 256, 256, 0, stream>>>(out, out_size);

    // CSR build
    hist_kernel<<<(E + 255) / 256, 256, 0, stream>>>(dst, deg_i, E);
    scan_kernel<<<1, 1024, 0, stream>>>(deg_i, row_start, cursor, N);
    place_kernel<<<(E + 255) / 256, 256, 0, stream>>>(src, dst, cursor, sorted_src, E);

    // layer 1
    gather1_kernel<<<(N + 3) / 4, 256, 0, stream>>>(x, votes, row_start, sorted_src, agg1, N);
    gemm1_kernel<<<(N + NP1 - 1) / NP1, 128, 0, stream>>>(x, votes, agg1, W1l, b1, W1r, h1, N);

    // layer 2
    gather2_kernel<<<(N + 3) / 4, 256, 0, stream>>>(h1, row_start, sorted_src, agg2, N);
    gemm2_kernel<<<(N + NP2 - 1) / NP2, 64, 0, stream>>>(h1, agg2, W2l, b2, W2r, h2, N);

    // pool
    {
        long long tot = (long long)N * OUTD;
        int blocks = (int)((tot + 255) / 256);
        segmax_kernel<<<blocks, 256, 0, stream>>>(h2, batch, out, N);
    }
}

// Round 3
// 463.763 us; speedup vs baseline: 2.1571x; 1.2661x over previous
//
#include <hip/hip_runtime.h>
#include <hip/hip_bf16.h>

#define IN_F 108   // concat(x[107], votes[1])
#define XD   107
#define HID  128
#define OUTD 64
#define H1S  132   // padded LDS stride for 128-wide rows (bank-conflict break)

typedef unsigned short ushort_t;
typedef unsigned int uint_t;

__device__ inline void atomicMaxF(float* addr, float val) {
    if (val >= 0.f) atomicMax((int*)addr, __float_as_int(val));
    else            atomicMin((unsigned int*)addr, __float_as_uint(val));
}

__device__ inline ushort_t f2bf(float f) {
    uint_t b = __float_as_uint(f);
    return (ushort_t)((b + 0x7fffu + ((b >> 16) & 1u)) >> 16);   // RNE
}

__device__ inline float4 fma4(float a, const float4 b, float4 c) {
    c.x += a * b.x; c.y += a * b.y; c.z += a * b.z; c.w += a * b.w; return c;
}

__global__ void init_out_kernel(float* out, int n) {
    int i = blockIdx.x * 256 + threadIdx.x;
    if (i < n) out[i] = -__builtin_inff();
}

// ---- CSR build ----------------------------------------------------------
__global__ void hist_kernel(const int* __restrict__ dst, int* __restrict__ deg_i, int E) {
    int e = blockIdx.x * 256 + threadIdx.x;
    if (e < E) atomicAdd(&deg_i[dst[e]], 1);
}

__global__ __launch_bounds__(1024) void scan_kernel(const int* __restrict__ deg_i,
                                                    int* __restrict__ row_start,
                                                    int* __restrict__ cursor, int N) {
    __shared__ int s[1024];
    int tid = threadIdx.x;
    int per = (N + 1023) / 1024;
    int begin = tid * per;
    int end = min(begin + per, N);
    int sum = 0;
    for (int i = begin; i < end; ++i) sum += deg_i[i];
    s[tid] = sum;
    __syncthreads();
    for (int d = 1; d < 1024; d <<= 1) {
        int t = (tid >= d) ? s[tid - d] : 0;
        __syncthreads();
        s[tid] += t;
        __syncthreads();
    }
    int off = s[tid] - sum;
    for (int i = begin; i < end; ++i) {
        row_start[i] = off;
        cursor[i] = off;
        off += deg_i[i];
    }
    if (tid == 1023) row_start[N] = s[1023];
}

__global__ void place_kernel(const int* __restrict__ src, const int* __restrict__ dst,
                             int* __restrict__ cursor, int* __restrict__ sorted_src, int E) {
    int e = blockIdx.x * 256 + threadIdx.x;
    if (e >= E) return;
    int pos = atomicAdd(&cursor[dst[e]], 1);
    sorted_src[pos] = src[e];
}

// ---- bf16 copy of h0 ----------------------------------------------------
__global__ void convert_kernel(const float* __restrict__ x, const float* __restrict__ votes,
                               ushort_t* __restrict__ xb, int N) {
    int idx = blockIdx.x * 256 + threadIdx.x;
    if (idx >= N * IN_F) return;
    int n = idx / IN_F, f = idx - n * IN_F;
    float v = (f < XD) ? x[n * XD + f] : votes[n];
    xb[idx] = f2bf(v);
}

// ---- gather-mean layer 1 (bf16 input, f32 accum, pre-divided output) ----
// wave per node; half-wave per neighbor (2 neighbors/iter); lane covers 4 feats
__global__ __launch_bounds__(256) void gather1_kernel(
        const ushort_t* __restrict__ xb,
        const int* __restrict__ row_start, const int* __restrict__ sorted_src,
        float* __restrict__ agg1, int N) {
    int node = (blockIdx.x * 256 + threadIdx.x) >> 6;
    int lane = threadIdx.x & 63;
    if (node >= N) return;
    int rs = row_start[node], re = row_start[node + 1];
    int h  = lane >> 5;        // neighbor parity
    int l2 = lane & 31;        // feature group; active < 27
    float a0 = 0.f, a1 = 0.f, a2 = 0.f, a3 = 0.f;
    for (int k0 = rs; k0 < re; k0 += 64) {
        int cnt = min(64, re - k0);
        int sl = sorted_src[k0 + min(lane, cnt - 1)];
        for (int t = 0; t < cnt; t += 2) {
            int tt = min(t + h, cnt - 1);
            int s = __shfl(sl, tt);               // all lanes active here
            if (t + h < cnt && l2 < 27) {
                uint2 w = *(const uint2*)(xb + s * IN_F + 4 * l2);
                a0 += __uint_as_float(w.x << 16);
                a1 += __uint_as_float(w.x & 0xffff0000u);
                a2 += __uint_as_float(w.y << 16);
                a3 += __uint_as_float(w.y & 0xffff0000u);
            }
        }
    }
    a0 += __shfl_xor(a0, 32);
    a1 += __shfl_xor(a1, 32);
    a2 += __shfl_xor(a2, 32);
    a3 += __shfl_xor(a3, 32);
    float inv = 1.f / fmaxf((float)(re - rs), 1.f);
    if (lane < 27) {
        float4 r = make_float4(a0 * inv, a1 * inv, a2 * inv, a3 * inv);
        *(float4*)(agg1 + node * IN_F + 4 * lane) = r;
    }
}

// ---- gather-mean of u (bf16, 64 dims): quarter-wave per neighbor --------
__global__ __launch_bounds__(256) void gatheru_kernel(
        const ushort_t* __restrict__ ub,
        const int* __restrict__ row_start, const int* __restrict__ sorted_src,
        float* __restrict__ aggu, int N) {
    int node = (blockIdx.x * 256 + threadIdx.x) >> 6;
    int lane = threadIdx.x & 63;
    if (node >= N) return;
    int rs = row_start[node], re = row_start[node + 1];
    int g  = lane >> 4;        // 0..3 neighbor slot
    int l4 = lane & 15;        // 16 lanes x 4 feats = 64
    float a0 = 0.f, a1 = 0.f, a2 = 0.f, a3 = 0.f;
    for (int k0 = rs; k0 < re; k0 += 64) {
        int cnt = min(64, re - k0);
        int sl = sorted_src[k0 + min(lane, cnt - 1)];
        for (int t = 0; t < cnt; t += 4) {
            int tt = min(t + g, cnt - 1);
            int s = __shfl(sl, tt);
            if (t + g < cnt) {
                uint2 w = *(const uint2*)(ub + (s << 6) + 4 * l4);
                a0 += __uint_as_float(w.x << 16);
                a1 += __uint_as_float(w.x & 0xffff0000u);
                a2 += __uint_as_float(w.y << 16);
                a3 += __uint_as_float(w.y & 0xffff0000u);
            }
        }
    }
    a0 += __shfl_xor(a0, 16); a0 += __shfl_xor(a0, 32);
    a1 += __shfl_xor(a1, 16); a1 += __shfl_xor(a1, 32);
    a2 += __shfl_xor(a2, 16); a2 += __shfl_xor(a2, 32);
    a3 += __shfl_xor(a3, 16); a3 += __shfl_xor(a3, 32);
    float inv = 1.f / fmaxf((float)(re - rs), 1.f);
    if (lane < 16) {
        *(float4*)(aggu + (node << 6) + 4 * lane) =
            make_float4(a0 * inv, a1 * inv, a2 * inv, a3 * inv);
    }
}

// ---- layer-1 dense (register-tiled) + fused u = h1 @ W2l ----------------
// block 256 thr, 32 nodes. phase1: thread = (jq 0..31 -> 4 j's) x (mq 0..7 -> 4 m's)
#define T1_M 32
__global__ __launch_bounds__(256) void gemm1_kernel(
        const float* __restrict__ x, const float* __restrict__ votes,
        const float* __restrict__ agg1,
        const float* __restrict__ W1l, const float* __restrict__ b1,
        const float* __restrict__ W1r, const float* __restrict__ W2l,
        float* __restrict__ h1, ushort_t* __restrict__ ub, int N) {
    __shared__ float smem[2 * T1_M * IN_F];          // 27.6 KB; phase2 reuses [32][H1S]
    float* sh_ag = smem;
    float* sh_h0 = smem + T1_M * IN_F;
    int n0 = blockIdx.x * T1_M;
    for (int i = threadIdx.x; i < T1_M * IN_F; i += 256) {
        int m = i / IN_F, k = i - m * IN_F;
        int n = n0 + m;
        float h0v = 0.f, agv = 0.f;
        if (n < N) {
            h0v = (k < XD) ? x[n * XD + k] : votes[n];
            agv = agg1[n * IN_F + k];
        }
        sh_h0[i] = h0v;
        sh_ag[i] = agv;
    }
    __syncthreads();

    int jq = threadIdx.x & 31;          // j0 = jq*4
    int mq = threadIdx.x >> 5;          // m = mq*4 + mm
    float4 acc[4] = {};                 // [mm] over j-vector
    const float* wl = W1l + jq * 4;
    const float* wr = W1r + jq * 4;
    for (int k = 0; k < IN_F; k += 4) {
        float4 wlv[4], wrv[4];
#pragma unroll
        for (int kk = 0; kk < 4; ++kk) {
            wlv[kk] = *(const float4*)(wl + (k + kk) * HID);
            wrv[kk] = *(const float4*)(wr + (k + kk) * HID);
        }
#pragma unroll
        for (int mm = 0; mm < 4; ++mm) {
            const int row = (mq * 4 + mm) * IN_F + k;
            float4 ag = *(const float4*)(sh_ag + row);
            float4 h0 = *(const float4*)(sh_h0 + row);
            acc[mm] = fma4(ag.x, wlv[0], acc[mm]);
            acc[mm] = fma4(ag.y, wlv[1], acc[mm]);
            acc[mm] = fma4(ag.z, wlv[2], acc[mm]);
            acc[mm] = fma4(ag.w, wlv[3], acc[mm]);
            acc[mm] = fma4(h0.x, wrv[0], acc[mm]);
            acc[mm] = fma4(h0.y, wrv[1], acc[mm]);
            acc[mm] = fma4(h0.z, wrv[2], acc[mm]);
            acc[mm] = fma4(h0.w, wrv[3], acc[mm]);
        }
    }
    float4 bv = *(const float4*)(b1 + jq * 4);
    float4 rr[4];
#pragma unroll
    for (int mm = 0; mm < 4; ++mm) {
        rr[mm].x = fmaxf(acc[mm].x + bv.x, 0.f);
        rr[mm].y = fmaxf(acc[mm].y + bv.y, 0.f);
        rr[mm].z = fmaxf(acc[mm].z + bv.z, 0.f);
        rr[mm].w = fmaxf(acc[mm].w + bv.w, 0.f);
        int n = n0 + mq * 4 + mm;
        if (n < N) *(float4*)(h1 + n * HID + jq * 4) = rr[mm];
    }

    // phase 2: u = relu(h1_tile) @ W2l  -> bf16
    __syncthreads();                                    // done reading sh_ag/sh_h0
#pragma unroll
    for (int mm = 0; mm < 4; ++mm)
        *(float4*)(smem + (mq * 4 + mm) * H1S + jq * 4) = rr[mm];
    __syncthreads();

    int jq2 = threadIdx.x & 15;         // j0 = jq2*4 (64 j)
    int mq2 = threadIdx.x >> 4;         // m = mq2*2 + mm (32 m)
    float4 acc2[2] = {};
    const float* w2 = W2l + jq2 * 4;
    for (int k = 0; k < HID; k += 4) {
        float4 wv[4];
#pragma unroll
        for (int kk = 0; kk < 4; ++kk)
            wv[kk] = *(const float4*)(w2 + (k + kk) * OUTD);
#pragma unroll
        for (int mm = 0; mm < 2; ++mm) {
            float4 hv = *(const float4*)(smem + (mq2 * 2 + mm) * H1S + k);
            acc2[mm] = fma4(hv.x, wv[0], acc2[mm]);
            acc2[mm] = fma4(hv.y, wv[1], acc2[mm]);
            acc2[mm] = fma4(hv.z, wv[2], acc2[mm]);
            acc2[mm] = fma4(hv.w, wv[3], acc2[mm]);
        }
    }
#pragma unroll
    for (int mm = 0; mm < 2; ++mm) {
        int n = n0 + mq2 * 2 + mm;
        if (n < N) {
            ushort4 p;
            p.x = f2bf(acc2[mm].x);
            p.y = f2bf(acc2[mm].y);
            p.z = f2bf(acc2[mm].z);
            p.w = f2bf(acc2[mm].w);
            *(ushort4*)(ub + (n << 6) + jq2 * 4) = p;
        }
    }
}

// ---- layer-2 dense: h2 = aggu + h1 @ W2r + b2 ---------------------------
__global__ __launch_bounds__(256) void gemm2_kernel(
        const float* __restrict__ h1, const float* __restrict__ aggu,
        const float* __restrict__ W2r, const float* __restrict__ b2,
        float* __restrict__ h2, int N) {
    __shared__ float sh[32 * H1S];
    int n0 = blockIdx.x * 32;
    for (int i = threadIdx.x; i < 32 * HID; i += 256) {
        int m = i >> 7, k = i & 127;
        int n = n0 + m;
        sh[m * H1S + k] = (n < N) ? h1[n * HID + k] : 0.f;
    }
    __syncthreads();
    int jq = threadIdx.x & 15;          // j0 = jq*4
    int mq = threadIdx.x >> 4;          // m = mq*2 + mm
    float4 acc[2] = {};
    const float* w = W2r + jq * 4;
    for (int k = 0; k < HID; k += 4) {
        float4 wv[4];
#pragma unroll
        for (int kk = 0; kk < 4; ++kk)
            wv[kk] = *(const float4*)(w + (k + kk) * OUTD);
#pragma unroll
        for (int mm = 0; mm < 2; ++mm) {
            float4 hv = *(const float4*)(sh + (mq * 2 + mm) * H1S + k);
            acc[mm] = fma4(hv.x, wv[0], acc[mm]);
            acc[mm] = fma4(hv.y, wv[1], acc[mm]);
            acc[mm] = fma4(hv.z, wv[2], acc[mm]);
            acc[mm] = fma4(hv.w, wv[3], acc[mm]);
        }
    }
    float4 bv = *(const float4*)(b2 + jq * 4);
#pragma unroll
    for (int mm = 0; mm < 2; ++mm) {
        int n = n0 + mq * 2 + mm;
        if (n < N) {
            float4 u4 = *(const float4*)(aggu + (n << 6) + jq * 4);
            float4 r;
            r.x = acc[mm].x + u4.x + bv.x;
            r.y = acc[mm].y + u4.y + bv.y;
            r.z = acc[mm].z + u4.z + bv.z;
            r.w = acc[mm].w + u4.w + bv.w;
            *(float4*)(h2 + (n << 6) + jq * 4) = r;
        }
    }
}

__global__ void segmax_kernel(const float* __restrict__ h2, const int* __restrict__ batch,
                              float* __restrict__ out, int N) {
    int idx = blockIdx.x * 256 + threadIdx.x;
    if (idx >= N * OUTD) return;
    int n = idx >> 6;
    int j = idx & 63;
    atomicMaxF(&out[(batch[n] << 6) + j], h2[idx]);
}

static inline size_t align256(size_t v) { return (v + 255) & ~(size_t)255; }

extern "C" void kernel_launch(void* const* d_in, const int* in_sizes, int n_in,
                              void* d_out, int out_size, void* d_ws, size_t ws_size,
                              hipStream_t stream) {
    const float* x     = (const float*)d_in[0];
    const float* votes = (const float*)d_in[1];
    const int*   eidx  = (const int*)d_in[2];
    const int*   batch = (const int*)d_in[3];
    const float* W1l   = (const float*)d_in[4];
    const float* b1    = (const float*)d_in[5];
    const float* W1r   = (const float*)d_in[6];
    const float* W2l   = (const float*)d_in[7];
    const float* b2    = (const float*)d_in[8];
    const float* W2r   = (const float*)d_in[9];
    float* out = (float*)d_out;

    const int N = in_sizes[1];
    const int E = in_sizes[2] / 2;
    const int* src = eidx;
    const int* dst = eidx + E;

    char* ws = (char*)d_ws;
    size_t off = 0;
    int* deg_i      = (int*)(ws + off); off = align256(off + (size_t)N * 4);
    int* row_start  = (int*)(ws + off); off = align256(off + (size_t)(N + 1) * 4);
    int* cursor     = (int*)(ws + off); off = align256(off + (size_t)N * 4);
    int* sorted_src = (int*)(ws + off); off = align256(off + (size_t)E * 4);
    ushort_t* xb    = (ushort_t*)(ws + off); off = align256(off + (size_t)N * IN_F * 2);
    float* h1       = (float*)(ws + off); off = align256(off + (size_t)N * HID * 4);
    ushort_t* ub    = (ushort_t*)(ws + off); off = align256(off + (size_t)N * OUTD * 2);
    float* aggu     = (float*)(ws + off); off = align256(off + (size_t)N * OUTD * 4);
    float* agg1     = (float*)(ws + off);   // N*IN_F*4; reused as h2 (N*64*4) afterwards
    float* h2       = agg1;

    hipMemsetAsync(deg_i, 0, (size_t)N * 4, stream);
    init_out_kernel<<<(out_size + 255) / 256, 256, 0, stream>>>(out, out_size);

    // CSR
    hist_kernel<<<(E + 255) / 256, 256, 0, stream>>>(dst, deg_i, E);
    scan_kernel<<<1, 1024, 0, stream>>>(deg_i, row_start, cursor, N);
    place_kernel<<<(E + 255) / 256, 256, 0, stream>>>(src, dst, cursor, sorted_src, E);

    // h0 -> bf16
    convert_kernel<<<(N * IN_F + 255) / 256, 256, 0, stream>>>(x, votes, xb, N);

    // layer 1
    gather1_kernel<<<(N + 3) / 4, 256, 0, stream>>>(xb, row_start, sorted_src, agg1, N);
    gemm1_kernel<<<(N + T1_M - 1) / T1_M, 256, 0, stream>>>(x, votes, agg1, W1l, b1, W1r,
                                                            W2l, h1, ub, N);
    // layer 2 (u already transformed; gather 64 dims)
    gatheru_kernel<<<(N + 3) / 4, 256, 0, stream>>>(ub, row_start, sorted_src, aggu, N);
    gemm2_kernel<<<(N + 31) / 32, 256, 0, stream>>>(h1, aggu, W2r, b2, h2, N);

    // pool
    segmax_kernel<<<(N * OUTD + 255) / 256, 256, 0, stream>>>(h2, batch, out, N);
}

// Round 4
// 380.556 us; speedup vs baseline: 2.6288x; 1.2186x over previous
//
#include <hip/hip_runtime.h>
#include <hip/hip_bf16.h>

#define IN_F 108   // concat(x[107], votes[1])
#define XD   107
#define HID  128
#define OUTD 64
#define H1S  132   // padded LDS stride for 128-wide rows
#define CHUNK 1024 // scan chunk per block

typedef unsigned short ushort_t;
typedef unsigned int uint_t;

__device__ inline void atomicMaxF(float* addr, float val) {
    if (val >= 0.f) atomicMax((int*)addr, __float_as_int(val));
    else            atomicMin((unsigned int*)addr, __float_as_uint(val));
}

__device__ inline ushort_t f2bf(float f) {
    uint_t b = __float_as_uint(f);
    return (ushort_t)((b + 0x7fffu + ((b >> 16) & 1u)) >> 16);   // RNE
}

__device__ inline float4 fma4(float a, const float4 b, float4 c) {
    c.x += a * b.x; c.y += a * b.y; c.z += a * b.z; c.w += a * b.w; return c;
}

__global__ void init_out_kernel(float* out, int n) {
    int i = blockIdx.x * 256 + threadIdx.x;
    if (i < n) out[i] = -__builtin_inff();
}

// ---- CSR build ----------------------------------------------------------
__global__ void hist_kernel(const int* __restrict__ dst, int* __restrict__ deg_i, int E) {
    int e = blockIdx.x * 256 + threadIdx.x;
    if (e < E) atomicAdd(&deg_i[dst[e]], 1);
}

// (1) per-chunk sums
__global__ __launch_bounds__(256) void chunk_sum_kernel(const int* __restrict__ deg_i,
                                                        int* __restrict__ bsum, int N) {
    int base = blockIdx.x * CHUNK;
    int v = 0;
    for (int i = threadIdx.x; i < CHUNK; i += 256) {
        int idx = base + i;
        if (idx < N) v += deg_i[idx];
    }
#pragma unroll
    for (int d = 1; d < 64; d <<= 1) v += __shfl_xor(v, d);
    __shared__ int red[4];
    int wid = threadIdx.x >> 6;
    if ((threadIdx.x & 63) == 0) red[wid] = v;
    __syncthreads();
    if (threadIdx.x == 0) bsum[blockIdx.x] = red[0] + red[1] + red[2] + red[3];
}

// (2) exclusive scan of chunk sums (one wave, sequential carry)
__global__ __launch_bounds__(64) void scan_bsum_kernel(const int* __restrict__ bsum,
                                                       int* __restrict__ bsum_ex, int nb) {
    int lane = threadIdx.x;
    int carry = 0;
    for (int b = 0; b < nb; b += 64) {
        int i = b + lane;
        int orig = (i < nb) ? bsum[i] : 0;
        int v = orig;
#pragma unroll
        for (int d = 1; d < 64; d <<= 1) {
            int t = __shfl_up(v, d);
            if (lane >= d) v += t;
        }
        if (i < nb) bsum_ex[i] = carry + v - orig;
        carry += __shfl(v, 63);
    }
}

// (3) per-chunk local exclusive scan + offset -> row_start, cursor
__global__ __launch_bounds__(256) void write_rows_kernel(const int* __restrict__ deg_i,
                                                         const int* __restrict__ bsum_ex,
                                                         int* __restrict__ row_start,
                                                         int* __restrict__ cursor,
                                                         int N, int E) {
    __shared__ int s[256];
    int base = blockIdx.x * CHUNK;
    int i0 = base + threadIdx.x * 4;
    int d0 = 0, d1 = 0, d2 = 0, d3 = 0;
    if (i0 + 3 < N) {
        int4 q = *(const int4*)(deg_i + i0);
        d0 = q.x; d1 = q.y; d2 = q.z; d3 = q.w;
    } else {
        if (i0 + 0 < N) d0 = deg_i[i0 + 0];
        if (i0 + 1 < N) d1 = deg_i[i0 + 1];
        if (i0 + 2 < N) d2 = deg_i[i0 + 2];
        if (i0 + 3 < N) d3 = deg_i[i0 + 3];
    }
    int tsum = d0 + d1 + d2 + d3;
    s[threadIdx.x] = tsum;
    __syncthreads();
    for (int d = 1; d < 256; d <<= 1) {
        int t = (threadIdx.x >= d) ? s[threadIdx.x - d] : 0;
        __syncthreads();
        s[threadIdx.x] += t;
        __syncthreads();
    }
    int off = bsum_ex[blockIdx.x] + s[threadIdx.x] - tsum;
    if (i0 + 0 < N) { row_start[i0 + 0] = off; cursor[i0 + 0] = off; off += d0; }
    if (i0 + 1 < N) { row_start[i0 + 1] = off; cursor[i0 + 1] = off; off += d1; }
    if (i0 + 2 < N) { row_start[i0 + 2] = off; cursor[i0 + 2] = off; off += d2; }
    if (i0 + 3 < N) { row_start[i0 + 3] = off; cursor[i0 + 3] = off; off += d3; }
    if (blockIdx.x == 0 && threadIdx.x == 0) row_start[N] = E;
}

__global__ void place_kernel(const int* __restrict__ src, const int* __restrict__ dst,
                             int* __restrict__ cursor, int* __restrict__ sorted_src, int E) {
    int e = blockIdx.x * 256 + threadIdx.x;
    if (e >= E) return;
    int pos = atomicAdd(&cursor[dst[e]], 1);
    sorted_src[pos] = src[e];
}

// ---- bf16 copy of h0 ----------------------------------------------------
__global__ void convert_kernel(const float* __restrict__ x, const float* __restrict__ votes,
                               ushort_t* __restrict__ xb, int N) {
    int idx = blockIdx.x * 256 + threadIdx.x;
    if (idx >= N * IN_F) return;
    int n = idx / IN_F, f = idx - n * IN_F;
    float v = (f < XD) ? x[n * XD + f] : votes[n];
    xb[idx] = f2bf(v);
}

// ---- gather-mean layer 1 (bf16 input, f32 accum, pre-divided output) ----
__global__ __launch_bounds__(256) void gather1_kernel(
        const ushort_t* __restrict__ xb,
        const int* __restrict__ row_start, const int* __restrict__ sorted_src,
        float* __restrict__ agg1, int N) {
    int node = (blockIdx.x * 256 + threadIdx.x) >> 6;
    int lane = threadIdx.x & 63;
    if (node >= N) return;
    int rs = row_start[node], re = row_start[node + 1];
    int h  = lane >> 5;        // neighbor parity
    int l2 = lane & 31;        // feature group; active < 27
    float a0 = 0.f, a1 = 0.f, a2 = 0.f, a3 = 0.f;
    for (int k0 = rs; k0 < re; k0 += 64) {
        int cnt = min(64, re - k0);
        int sl = sorted_src[k0 + min(lane, cnt - 1)];
        for (int t = 0; t < cnt; t += 2) {
            int tt = min(t + h, cnt - 1);
            int s = __shfl(sl, tt);
            if (t + h < cnt && l2 < 27) {
                uint2 w = *(const uint2*)(xb + s * IN_F + 4 * l2);
                a0 += __uint_as_float(w.x << 16);
                a1 += __uint_as_float(w.x & 0xffff0000u);
                a2 += __uint_as_float(w.y << 16);
                a3 += __uint_as_float(w.y & 0xffff0000u);
            }
        }
    }
    a0 += __shfl_xor(a0, 32);
    a1 += __shfl_xor(a1, 32);
    a2 += __shfl_xor(a2, 32);
    a3 += __shfl_xor(a3, 32);
    float inv = 1.f / fmaxf((float)(re - rs), 1.f);
    if (lane < 27) {
        float4 r = make_float4(a0 * inv, a1 * inv, a2 * inv, a3 * inv);
        *(float4*)(agg1 + node * IN_F + 4 * lane) = r;
    }
}

// ---- gather-mean of u (bf16, 64 dims): quarter-wave per neighbor --------
__global__ __launch_bounds__(256) void gatheru_kernel(
        const ushort_t* __restrict__ ub,
        const int* __restrict__ row_start, const int* __restrict__ sorted_src,
        float* __restrict__ aggu, int N) {
    int node = (blockIdx.x * 256 + threadIdx.x) >> 6;
    int lane = threadIdx.x & 63;
    if (node >= N) return;
    int rs = row_start[node], re = row_start[node + 1];
    int g  = lane >> 4;        // 0..3 neighbor slot
    int l4 = lane & 15;        // 16 lanes x 4 feats = 64
    float a0 = 0.f, a1 = 0.f, a2 = 0.f, a3 = 0.f;
    for (int k0 = rs; k0 < re; k0 += 64) {
        int cnt = min(64, re - k0);
        int sl = sorted_src[k0 + min(lane, cnt - 1)];
        for (int t = 0; t < cnt; t += 4) {
            int tt = min(t + g, cnt - 1);
            int s = __shfl(sl, tt);
            if (t + g < cnt) {
                uint2 w = *(const uint2*)(ub + (s << 6) + 4 * l4);
                a0 += __uint_as_float(w.x << 16);
                a1 += __uint_as_float(w.x & 0xffff0000u);
                a2 += __uint_as_float(w.y << 16);
                a3 += __uint_as_float(w.y & 0xffff0000u);
            }
        }
    }
    a0 += __shfl_xor(a0, 16); a0 += __shfl_xor(a0, 32);
    a1 += __shfl_xor(a1, 16); a1 += __shfl_xor(a1, 32);
    a2 += __shfl_xor(a2, 16); a2 += __shfl_xor(a2, 32);
    a3 += __shfl_xor(a3, 16); a3 += __shfl_xor(a3, 32);
    float inv = 1.f / fmaxf((float)(re - rs), 1.f);
    if (lane < 16) {
        *(float4*)(aggu + (node << 6) + 4 * lane) =
            make_float4(a0 * inv, a1 * inv, a2 * inv, a3 * inv);
    }
}

// ---- layer-1 dense (register-tiled) + fused u = h1 @ W2l ----------------
#define T1_M 32
__global__ __launch_bounds__(256) void gemm1_kernel(
        const float* __restrict__ x, const float* __restrict__ votes,
        const float* __restrict__ agg1,
        const float* __restrict__ W1l, const float* __restrict__ b1,
        const float* __restrict__ W1r, const float* __restrict__ W2l,
        float* __restrict__ h1, ushort_t* __restrict__ ub, int N) {
    __shared__ float smem[2 * T1_M * IN_F];          // 27.6 KB; phase2 reuses [32][H1S]
    float* sh_ag = smem;
    float* sh_h0 = smem + T1_M * IN_F;
    int n0 = blockIdx.x * T1_M;
    for (int i = threadIdx.x; i < T1_M * IN_F; i += 256) {
        int m = i / IN_F, k = i - m * IN_F;
        int n = n0 + m;
        float h0v = 0.f, agv = 0.f;
        if (n < N) {
            h0v = (k < XD) ? x[n * XD + k] : votes[n];
            agv = agg1[n * IN_F + k];
        }
        sh_h0[i] = h0v;
        sh_ag[i] = agv;
    }
    __syncthreads();

    int jq = threadIdx.x & 31;          // j0 = jq*4
    int mq = threadIdx.x >> 5;          // m = mq*4 + mm
    float4 acc[4] = {};
    const float* wl = W1l + jq * 4;
    const float* wr = W1r + jq * 4;
    for (int k = 0; k < IN_F; k += 4) {
        float4 wlv[4], wrv[4];
#pragma unroll
        for (int kk = 0; kk < 4; ++kk) {
            wlv[kk] = *(const float4*)(wl + (k + kk) * HID);
            wrv[kk] = *(const float4*)(wr + (k + kk) * HID);
        }
#pragma unroll
        for (int mm = 0; mm < 4; ++mm) {
            const int row = (mq * 4 + mm) * IN_F + k;
            float4 ag = *(const float4*)(sh_ag + row);
            float4 h0 = *(const float4*)(sh_h0 + row);
            acc[mm] = fma4(ag.x, wlv[0], acc[mm]);
            acc[mm] = fma4(ag.y, wlv[1], acc[mm]);
            acc[mm] = fma4(ag.z, wlv[2], acc[mm]);
            acc[mm] = fma4(ag.w, wlv[3], acc[mm]);
            acc[mm] = fma4(h0.x, wrv[0], acc[mm]);
            acc[mm] = fma4(h0.y, wrv[1], acc[mm]);
            acc[mm] = fma4(h0.z, wrv[2], acc[mm]);
            acc[mm] = fma4(h0.w, wrv[3], acc[mm]);
        }
    }
    float4 bv = *(const float4*)(b1 + jq * 4);
    float4 rr[4];
#pragma unroll
    for (int mm = 0; mm < 4; ++mm) {
        rr[mm].x = fmaxf(acc[mm].x + bv.x, 0.f);
        rr[mm].y = fmaxf(acc[mm].y + bv.y, 0.f);
        rr[mm].z = fmaxf(acc[mm].z + bv.z, 0.f);
        rr[mm].w = fmaxf(acc[mm].w + bv.w, 0.f);
        int n = n0 + mq * 4 + mm;
        if (n < N) *(float4*)(h1 + n * HID + jq * 4) = rr[mm];
    }

    // phase 2: u = relu(h1_tile) @ W2l  -> bf16
    __syncthreads();
#pragma unroll
    for (int mm = 0; mm < 4; ++mm)
        *(float4*)(smem + (mq * 4 + mm) * H1S + jq * 4) = rr[mm];
    __syncthreads();

    int jq2 = threadIdx.x & 15;         // j0 = jq2*4 (64 j)
    int mq2 = threadIdx.x >> 4;         // m = mq2*2 + mm (32 m)
    float4 acc2[2] = {};
    const float* w2 = W2l + jq2 * 4;
    for (int k = 0; k < HID; k += 4) {
        float4 wv[4];
#pragma unroll
        for (int kk = 0; kk < 4; ++kk)
            wv[kk] = *(const float4*)(w2 + (k + kk) * OUTD);
#pragma unroll
        for (int mm = 0; mm < 2; ++mm) {
            float4 hv = *(const float4*)(smem + (mq2 * 2 + mm) * H1S + k);
            acc2[mm] = fma4(hv.x, wv[0], acc2[mm]);
            acc2[mm] = fma4(hv.y, wv[1], acc2[mm]);
            acc2[mm] = fma4(hv.z, wv[2], acc2[mm]);
            acc2[mm] = fma4(hv.w, wv[3], acc2[mm]);
        }
    }
#pragma unroll
    for (int mm = 0; mm < 2; ++mm) {
        int n = n0 + mq2 * 2 + mm;
        if (n < N) {
            ushort4 p;
            p.x = f2bf(acc2[mm].x);
            p.y = f2bf(acc2[mm].y);
            p.z = f2bf(acc2[mm].z);
            p.w = f2bf(acc2[mm].w);
            *(ushort4*)(ub + (n << 6) + jq2 * 4) = p;
        }
    }
}

// ---- layer-2 dense: h2 = aggu + h1 @ W2r + b2 ---------------------------
__global__ __launch_bounds__(256) void gemm2_kernel(
        const float* __restrict__ h1, const float* __restrict__ aggu,
        const float* __restrict__ W2r, const float* __restrict__ b2,
        float* __restrict__ h2, int N) {
    __shared__ float sh[32 * H1S];
    int n0 = blockIdx.x * 32;
    for (int i = threadIdx.x; i < 32 * HID; i += 256) {
        int m = i >> 7, k = i & 127;
        int n = n0 + m;
        sh[m * H1S + k] = (n < N) ? h1[n * HID + k] : 0.f;
    }
    __syncthreads();
    int jq = threadIdx.x & 15;
    int mq = threadIdx.x >> 4;
    float4 acc[2] = {};
    const float* w = W2r + jq * 4;
    for (int k = 0; k < HID; k += 4) {
        float4 wv[4];
#pragma unroll
        for (int kk = 0; kk < 4; ++kk)
            wv[kk] = *(const float4*)(w + (k + kk) * OUTD);
#pragma unroll
        for (int mm = 0; mm < 2; ++mm) {
            float4 hv = *(const float4*)(sh + (mq * 2 + mm) * H1S + k);
            acc[mm] = fma4(hv.x, wv[0], acc[mm]);
            acc[mm] = fma4(hv.y, wv[1], acc[mm]);
            acc[mm] = fma4(hv.z, wv[2], acc[mm]);
            acc[mm] = fma4(hv.w, wv[3], acc[mm]);
        }
    }
    float4 bv = *(const float4*)(b2 + jq * 4);
#pragma unroll
    for (int mm = 0; mm < 2; ++mm) {
        int n = n0 + mq * 2 + mm;
        if (n < N) {
            float4 u4 = *(const float4*)(aggu + (n << 6) + jq * 4);
            float4 r;
            r.x = acc[mm].x + u4.x + bv.x;
            r.y = acc[mm].y + u4.y + bv.y;
            r.z = acc[mm].z + u4.z + bv.z;
            r.w = acc[mm].w + u4.w + bv.w;
            *(float4*)(h2 + (n << 6) + jq * 4) = r;
        }
    }
}

__global__ void segmax_kernel(const float* __restrict__ h2, const int* __restrict__ batch,
                              float* __restrict__ out, int N) {
    int idx = blockIdx.x * 256 + threadIdx.x;
    if (idx >= N * OUTD) return;
    int n = idx >> 6;
    int j = idx & 63;
    atomicMaxF(&out[(batch[n] << 6) + j], h2[idx]);
}

static inline size_t align256(size_t v) { return (v + 255) & ~(size_t)255; }

extern "C" void kernel_launch(void* const* d_in, const int* in_sizes, int n_in,
                              void* d_out, int out_size, void* d_ws, size_t ws_size,
                              hipStream_t stream) {
    const float* x     = (const float*)d_in[0];
    const float* votes = (const float*)d_in[1];
    const int*   eidx  = (const int*)d_in[2];
    const int*   batch = (const int*)d_in[3];
    const float* W1l   = (const float*)d_in[4];
    const float* b1    = (const float*)d_in[5];
    const float* W1r   = (const float*)d_in[6];
    const float* W2l   = (const float*)d_in[7];
    const float* b2    = (const float*)d_in[8];
    const float* W2r   = (const float*)d_in[9];
    float* out = (float*)d_out;

    const int N = in_sizes[1];
    const int E = in_sizes[2] / 2;
    const int* src = eidx;
    const int* dst = eidx + E;
    const int nb = (N + CHUNK - 1) / CHUNK;

    char* ws = (char*)d_ws;
    size_t off = 0;
    int* deg_i      = (int*)(ws + off); off = align256(off + (size_t)N * 4);
    int* row_start  = (int*)(ws + off); off = align256(off + (size_t)(N + 1) * 4);
    int* cursor     = (int*)(ws + off); off = align256(off + (size_t)N * 4);
    int* bsum       = (int*)(ws + off); off = align256(off + (size_t)nb * 4);
    int* bsum_ex    = (int*)(ws + off); off = align256(off + (size_t)nb * 4);
    int* sorted_src = (int*)(ws + off); off = align256(off + (size_t)E * 4);
    ushort_t* xb    = (ushort_t*)(ws + off); off = align256(off + (size_t)N * IN_F * 2);
    float* h1       = (float*)(ws + off); off = align256(off + (size_t)N * HID * 4);
    ushort_t* ub    = (ushort_t*)(ws + off); off = align256(off + (size_t)N * OUTD * 2);
    float* aggu     = (float*)(ws + off); off = align256(off + (size_t)N * OUTD * 4);
    float* agg1     = (float*)(ws + off);   // N*IN_F*4; reused as h2 afterwards
    float* h2       = agg1;

    hipMemsetAsync(deg_i, 0, (size_t)N * 4, stream);
    init_out_kernel<<<(out_size + 255) / 256, 256, 0, stream>>>(out, out_size);

    // CSR
    hist_kernel<<<(E + 255) / 256, 256, 0, stream>>>(dst, deg_i, E);
    chunk_sum_kernel<<<nb, 256, 0, stream>>>(deg_i, bsum, N);
    scan_bsum_kernel<<<1, 64, 0, stream>>>(bsum, bsum_ex, nb);
    write_rows_kernel<<<nb, 256, 0, stream>>>(deg_i, bsum_ex, row_start, cursor, N, E);
    place_kernel<<<(E + 255) / 256, 256, 0, stream>>>(src, dst, cursor, sorted_src, E);

    // h0 -> bf16
    convert_kernel<<<(N * IN_F + 255) / 256, 256, 0, stream>>>(x, votes, xb, N);

    // layer 1
    gather1_kernel<<<(N + 3) / 4, 256, 0, stream>>>(xb, row_start, sorted_src, agg1, N);
    gemm1_kernel<<<(N + T1_M - 1) / T1_M, 256, 0, stream>>>(x, votes, agg1, W1l, b1, W1r,
                                                            W2l, h1, ub, N);
    // layer 2
    gatheru_kernel<<<(N + 3) / 4, 256, 0, stream>>>(ub, row_start, sorted_src, aggu, N);
    gemm2_kernel<<<(N + 31) / 32, 256, 0, stream>>>(h1, aggu, W2r, b2, h2, N);

    // pool
    segmax_kernel<<<(N * OUTD + 255) / 256, 256, 0, stream>>>(h2, batch, out, N);
}

// Round 5
// 333.626 us; speedup vs baseline: 2.9985x; 1.1407x over previous
//
#include <hip/hip_runtime.h>
#include <hip/hip_bf16.h>

#define IN_F 108   // concat(x[107], votes[1])
#define XD   107
#define HID  128
#define OUTD 64
#define H1S  132   // padded LDS stride for 128-wide rows
#define CHUNK 1024 // scan chunk per block
#define SEG_NODES 512

typedef unsigned short ushort_t;
typedef unsigned int uint_t;

__device__ inline void atomicMaxF(float* addr, float val) {
    if (val >= 0.f) atomicMax((int*)addr, __float_as_int(val));
    else            atomicMin((unsigned int*)addr, __float_as_uint(val));
}

__device__ inline ushort_t f2bf(float f) {
    uint_t b = __float_as_uint(f);
    return (ushort_t)((b + 0x7fffu + ((b >> 16) & 1u)) >> 16);   // RNE
}

__device__ inline float4 fma4(float a, const float4 b, float4 c) {
    c.x += a * b.x; c.y += a * b.y; c.z += a * b.z; c.w += a * b.w; return c;
}

__global__ void init_out_kernel(float* out, int n) {
    int i = blockIdx.x * 256 + threadIdx.x;
    if (i < n) out[i] = -__builtin_inff();
}

// ---- CSR build ----------------------------------------------------------
__global__ void hist_kernel(const int* __restrict__ dst, int* __restrict__ deg_i, int E) {
    int e = blockIdx.x * 256 + threadIdx.x;
    if (e < E) atomicAdd(&deg_i[dst[e]], 1);
}

__global__ __launch_bounds__(256) void chunk_sum_kernel(const int* __restrict__ deg_i,
                                                        int* __restrict__ bsum, int N) {
    int base = blockIdx.x * CHUNK;
    int v = 0;
    for (int i = threadIdx.x; i < CHUNK; i += 256) {
        int idx = base + i;
        if (idx < N) v += deg_i[idx];
    }
#pragma unroll
    for (int d = 1; d < 64; d <<= 1) v += __shfl_xor(v, d);
    __shared__ int red[4];
    int wid = threadIdx.x >> 6;
    if ((threadIdx.x & 63) == 0) red[wid] = v;
    __syncthreads();
    if (threadIdx.x == 0) bsum[blockIdx.x] = red[0] + red[1] + red[2] + red[3];
}

__global__ __launch_bounds__(64) void scan_bsum_kernel(const int* __restrict__ bsum,
                                                       int* __restrict__ bsum_ex, int nb) {
    int lane = threadIdx.x;
    int carry = 0;
    for (int b = 0; b < nb; b += 64) {
        int i = b + lane;
        int orig = (i < nb) ? bsum[i] : 0;
        int v = orig;
#pragma unroll
        for (int d = 1; d < 64; d <<= 1) {
            int t = __shfl_up(v, d);
            if (lane >= d) v += t;
        }
        if (i < nb) bsum_ex[i] = carry + v - orig;
        carry += __shfl(v, 63);
    }
}

__global__ __launch_bounds__(256) void write_rows_kernel(const int* __restrict__ deg_i,
                                                         const int* __restrict__ bsum_ex,
                                                         int* __restrict__ row_start,
                                                         int* __restrict__ cursor,
                                                         int N, int E) {
    __shared__ int s[256];
    int base = blockIdx.x * CHUNK;
    int i0 = base + threadIdx.x * 4;
    int d0 = 0, d1 = 0, d2 = 0, d3 = 0;
    if (i0 + 3 < N) {
        int4 q = *(const int4*)(deg_i + i0);
        d0 = q.x; d1 = q.y; d2 = q.z; d3 = q.w;
    } else {
        if (i0 + 0 < N) d0 = deg_i[i0 + 0];
        if (i0 + 1 < N) d1 = deg_i[i0 + 1];
        if (i0 + 2 < N) d2 = deg_i[i0 + 2];
        if (i0 + 3 < N) d3 = deg_i[i0 + 3];
    }
    int tsum = d0 + d1 + d2 + d3;
    s[threadIdx.x] = tsum;
    __syncthreads();
    for (int d = 1; d < 256; d <<= 1) {
        int t = (threadIdx.x >= d) ? s[threadIdx.x - d] : 0;
        __syncthreads();
        s[threadIdx.x] += t;
        __syncthreads();
    }
    int off = bsum_ex[blockIdx.x] + s[threadIdx.x] - tsum;
    if (i0 + 0 < N) { row_start[i0 + 0] = off; cursor[i0 + 0] = off; off += d0; }
    if (i0 + 1 < N) { row_start[i0 + 1] = off; cursor[i0 + 1] = off; off += d1; }
    if (i0 + 2 < N) { row_start[i0 + 2] = off; cursor[i0 + 2] = off; off += d2; }
    if (i0 + 3 < N) { row_start[i0 + 3] = off; cursor[i0 + 3] = off; off += d3; }
    if (blockIdx.x == 0 && threadIdx.x == 0) row_start[N] = E;
}

__global__ void place_kernel(const int* __restrict__ src, const int* __restrict__ dst,
                             int* __restrict__ cursor, int* __restrict__ sorted_src, int E) {
    int e = blockIdx.x * 256 + threadIdx.x;
    if (e >= E) return;
    int pos = atomicAdd(&cursor[dst[e]], 1);
    sorted_src[pos] = src[e];
}

// ---- bf16 copy of h0 ----------------------------------------------------
__global__ void convert_kernel(const float* __restrict__ x, const float* __restrict__ votes,
                               ushort_t* __restrict__ xb, int N) {
    int idx = blockIdx.x * 256 + threadIdx.x;
    if (idx >= N * IN_F) return;
    int n = idx / IN_F, f = idx - n * IN_F;
    float v = (f < XD) ? x[n * XD + f] : votes[n];
    xb[idx] = f2bf(v);
}

// ---- gather-mean layer 1 (bf16 input, f32 accum, pre-divided output) ----
__global__ __launch_bounds__(256) void gather1_kernel(
        const ushort_t* __restrict__ xb,
        const int* __restrict__ row_start, const int* __restrict__ sorted_src,
        float* __restrict__ agg1, int N) {
    int node = (blockIdx.x * 256 + threadIdx.x) >> 6;
    int lane = threadIdx.x & 63;
    if (node >= N) return;
    int rs = row_start[node], re = row_start[node + 1];
    int h  = lane >> 5;
    int l2 = lane & 31;
    float a0 = 0.f, a1 = 0.f, a2 = 0.f, a3 = 0.f;
    for (int k0 = rs; k0 < re; k0 += 64) {
        int cnt = min(64, re - k0);
        int sl = sorted_src[k0 + min(lane, cnt - 1)];
        for (int t = 0; t < cnt; t += 2) {
            int tt = min(t + h, cnt - 1);
            int s = __shfl(sl, tt);
            if (t + h < cnt && l2 < 27) {
                uint2 w = *(const uint2*)(xb + s * IN_F + 4 * l2);
                a0 += __uint_as_float(w.x << 16);
                a1 += __uint_as_float(w.x & 0xffff0000u);
                a2 += __uint_as_float(w.y << 16);
                a3 += __uint_as_float(w.y & 0xffff0000u);
            }
        }
    }
    a0 += __shfl_xor(a0, 32);
    a1 += __shfl_xor(a1, 32);
    a2 += __shfl_xor(a2, 32);
    a3 += __shfl_xor(a3, 32);
    float inv = 1.f / fmaxf((float)(re - rs), 1.f);
    if (lane < 27) {
        float4 r = make_float4(a0 * inv, a1 * inv, a2 * inv, a3 * inv);
        *(float4*)(agg1 + node * IN_F + 4 * lane) = r;
    }
}

// ---- gather-mean of u (bf16, 64 dims) -----------------------------------
__global__ __launch_bounds__(256) void gatheru_kernel(
        const ushort_t* __restrict__ ub,
        const int* __restrict__ row_start, const int* __restrict__ sorted_src,
        float* __restrict__ aggu, int N) {
    int node = (blockIdx.x * 256 + threadIdx.x) >> 6;
    int lane = threadIdx.x & 63;
    if (node >= N) return;
    int rs = row_start[node], re = row_start[node + 1];
    int g  = lane >> 4;
    int l4 = lane & 15;
    float a0 = 0.f, a1 = 0.f, a2 = 0.f, a3 = 0.f;
    for (int k0 = rs; k0 < re; k0 += 64) {
        int cnt = min(64, re - k0);
        int sl = sorted_src[k0 + min(lane, cnt - 1)];
        for (int t = 0; t < cnt; t += 4) {
            int tt = min(t + g, cnt - 1);
            int s = __shfl(sl, tt);
            if (t + g < cnt) {
                uint2 w = *(const uint2*)(ub + (s << 6) + 4 * l4);
                a0 += __uint_as_float(w.x << 16);
                a1 += __uint_as_float(w.x & 0xffff0000u);
                a2 += __uint_as_float(w.y << 16);
                a3 += __uint_as_float(w.y & 0xffff0000u);
            }
        }
    }
    a0 += __shfl_xor(a0, 16); a0 += __shfl_xor(a0, 32);
    a1 += __shfl_xor(a1, 16); a1 += __shfl_xor(a1, 32);
    a2 += __shfl_xor(a2, 16); a2 += __shfl_xor(a2, 32);
    a3 += __shfl_xor(a3, 16); a3 += __shfl_xor(a3, 32);
    float inv = 1.f / fmaxf((float)(re - rs), 1.f);
    if (lane < 16) {
        *(float4*)(aggu + (node << 6) + 4 * lane) =
            make_float4(a0 * inv, a1 * inv, a2 * inv, a3 * inv);
    }
}

// ---- layer-1 dense (register-tiled) + fused u = h1 @ W2l ----------------
#define T1_M 32
__global__ __launch_bounds__(256) void gemm1_kernel(
        const float* __restrict__ x, const float* __restrict__ votes,
        const float* __restrict__ agg1,
        const float* __restrict__ W1l, const float* __restrict__ b1,
        const float* __restrict__ W1r, const float* __restrict__ W2l,
        float* __restrict__ h1, ushort_t* __restrict__ ub, int N) {
    __shared__ float smem[2 * T1_M * IN_F];
    float* sh_ag = smem;
    float* sh_h0 = smem + T1_M * IN_F;
    int n0 = blockIdx.x * T1_M;
    for (int i = threadIdx.x; i < T1_M * IN_F; i += 256) {
        int m = i / IN_F, k = i - m * IN_F;
        int n = n0 + m;
        float h0v = 0.f, agv = 0.f;
        if (n < N) {
            h0v = (k < XD) ? x[n * XD + k] : votes[n];
            agv = agg1[n * IN_F + k];
        }
        sh_h0[i] = h0v;
        sh_ag[i] = agv;
    }
    __syncthreads();

    int jq = threadIdx.x & 31;
    int mq = threadIdx.x >> 5;
    float4 acc[4] = {};
    const float* wl = W1l + jq * 4;
    const float* wr = W1r + jq * 4;
    for (int k = 0; k < IN_F; k += 4) {
        float4 wlv[4], wrv[4];
#pragma unroll
        for (int kk = 0; kk < 4; ++kk) {
            wlv[kk] = *(const float4*)(wl + (k + kk) * HID);
            wrv[kk] = *(const float4*)(wr + (k + kk) * HID);
        }
#pragma unroll
        for (int mm = 0; mm < 4; ++mm) {
            const int row = (mq * 4 + mm) * IN_F + k;
            float4 ag = *(const float4*)(sh_ag + row);
            float4 h0 = *(const float4*)(sh_h0 + row);
            acc[mm] = fma4(ag.x, wlv[0], acc[mm]);
            acc[mm] = fma4(ag.y, wlv[1], acc[mm]);
            acc[mm] = fma4(ag.z, wlv[2], acc[mm]);
            acc[mm] = fma4(ag.w, wlv[3], acc[mm]);
            acc[mm] = fma4(h0.x, wrv[0], acc[mm]);
            acc[mm] = fma4(h0.y, wrv[1], acc[mm]);
            acc[mm] = fma4(h0.z, wrv[2], acc[mm]);
            acc[mm] = fma4(h0.w, wrv[3], acc[mm]);
        }
    }
    float4 bv = *(const float4*)(b1 + jq * 4);
    float4 rr[4];
#pragma unroll
    for (int mm = 0; mm < 4; ++mm) {
        rr[mm].x = fmaxf(acc[mm].x + bv.x, 0.f);
        rr[mm].y = fmaxf(acc[mm].y + bv.y, 0.f);
        rr[mm].z = fmaxf(acc[mm].z + bv.z, 0.f);
        rr[mm].w = fmaxf(acc[mm].w + bv.w, 0.f);
        int n = n0 + mq * 4 + mm;
        if (n < N) *(float4*)(h1 + n * HID + jq * 4) = rr[mm];
    }

    __syncthreads();
#pragma unroll
    for (int mm = 0; mm < 4; ++mm)
        *(float4*)(smem + (mq * 4 + mm) * H1S + jq * 4) = rr[mm];
    __syncthreads();

    int jq2 = threadIdx.x & 15;
    int mq2 = threadIdx.x >> 4;
    float4 acc2[2] = {};
    const float* w2 = W2l + jq2 * 4;
    for (int k = 0; k < HID; k += 4) {
        float4 wv[4];
#pragma unroll
        for (int kk = 0; kk < 4; ++kk)
            wv[kk] = *(const float4*)(w2 + (k + kk) * OUTD);
#pragma unroll
        for (int mm = 0; mm < 2; ++mm) {
            float4 hv = *(const float4*)(smem + (mq2 * 2 + mm) * H1S + k);
            acc2[mm] = fma4(hv.x, wv[0], acc2[mm]);
            acc2[mm] = fma4(hv.y, wv[1], acc2[mm]);
            acc2[mm] = fma4(hv.z, wv[2], acc2[mm]);
            acc2[mm] = fma4(hv.w, wv[3], acc2[mm]);
        }
    }
#pragma unroll
    for (int mm = 0; mm < 2; ++mm) {
        int n = n0 + mq2 * 2 + mm;
        if (n < N) {
            ushort4 p;
            p.x = f2bf(acc2[mm].x);
            p.y = f2bf(acc2[mm].y);
            p.z = f2bf(acc2[mm].z);
            p.w = f2bf(acc2[mm].w);
            *(ushort4*)(ub + (n << 6) + jq2 * 4) = p;
        }
    }
}

// ---- layer-2 dense: h2 = aggu + h1 @ W2r + b2 ---------------------------
__global__ __launch_bounds__(256) void gemm2_kernel(
        const float* __restrict__ h1, const float* __restrict__ aggu,
        const float* __restrict__ W2r, const float* __restrict__ b2,
        float* __restrict__ h2, int N) {
    __shared__ float sh[32 * H1S];
    int n0 = blockIdx.x * 32;
    for (int i = threadIdx.x; i < 32 * HID; i += 256) {
        int m = i >> 7, k = i & 127;
        int n = n0 + m;
        sh[m * H1S + k] = (n < N) ? h1[n * HID + k] : 0.f;
    }
    __syncthreads();
    int jq = threadIdx.x & 15;
    int mq = threadIdx.x >> 4;
    float4 acc[2] = {};
    const float* w = W2r + jq * 4;
    for (int k = 0; k < HID; k += 4) {
        float4 wv[4];
#pragma unroll
        for (int kk = 0; kk < 4; ++kk)
            wv[kk] = *(const float4*)(w + (k + kk) * OUTD);
#pragma unroll
        for (int mm = 0; mm < 2; ++mm) {
            float4 hv = *(const float4*)(sh + (mq * 2 + mm) * H1S + k);
            acc[mm] = fma4(hv.x, wv[0], acc[mm]);
            acc[mm] = fma4(hv.y, wv[1], acc[mm]);
            acc[mm] = fma4(hv.z, wv[2], acc[mm]);
            acc[mm] = fma4(hv.w, wv[3], acc[mm]);
        }
    }
    float4 bv = *(const float4*)(b2 + jq * 4);
#pragma unroll
    for (int mm = 0; mm < 2; ++mm) {
        int n = n0 + mq * 2 + mm;
        if (n < N) {
            float4 u4 = *(const float4*)(aggu + (n << 6) + jq * 4);
            float4 r;
            r.x = acc[mm].x + u4.x + bv.x;
            r.y = acc[mm].y + u4.y + bv.y;
            r.z = acc[mm].z + u4.z + bv.z;
            r.w = acc[mm].w + u4.w + bv.w;
            *(float4*)(h2 + (n << 6) + jq * 4) = r;
        }
    }
}

// ---- segment-max with run-length pre-reduction (batch is sorted) --------
// block = 4 node-lanes x 64 j-lanes over SEG_NODES consecutive nodes;
// per-thread running (graph,max), atomic only at graph boundaries.
__global__ __launch_bounds__(256) void segmax_kernel(
        const float* __restrict__ h2, const int* __restrict__ batch,
        float* __restrict__ out, int N) {
    int j  = threadIdx.x & 63;
    int nq = threadIdx.x >> 6;
    int n0 = blockIdx.x * SEG_NODES;
    int curg = -1;
    float curm = -__builtin_inff();
    for (int m = nq; m < SEG_NODES; m += 4) {
        int n = n0 + m;
        if (n >= N) break;
        int g = batch[n];
        float v = h2[(n << 6) + j];
        if (g != curg) {
            if (curg >= 0) atomicMaxF(&out[(curg << 6) + j], curm);
            curg = g;
            curm = v;
        } else {
            curm = fmaxf(curm, v);
        }
    }
    if (curg >= 0) atomicMaxF(&out[(curg << 6) + j], curm);
}

static inline size_t align256(size_t v) { return (v + 255) & ~(size_t)255; }

extern "C" void kernel_launch(void* const* d_in, const int* in_sizes, int n_in,
                              void* d_out, int out_size, void* d_ws, size_t ws_size,
                              hipStream_t stream) {
    const float* x     = (const float*)d_in[0];
    const float* votes = (const float*)d_in[1];
    const int*   eidx  = (const int*)d_in[2];
    const int*   batch = (const int*)d_in[3];
    const float* W1l   = (const float*)d_in[4];
    const float* b1    = (const float*)d_in[5];
    const float* W1r   = (const float*)d_in[6];
    const float* W2l   = (const float*)d_in[7];
    const float* b2    = (const float*)d_in[8];
    const float* W2r   = (const float*)d_in[9];
    float* out = (float*)d_out;

    const int N = in_sizes[1];
    const int E = in_sizes[2] / 2;
    const int* src = eidx;
    const int* dst = eidx + E;
    const int nb = (N + CHUNK - 1) / CHUNK;

    char* ws = (char*)d_ws;
    size_t off = 0;
    int* deg_i      = (int*)(ws + off); off = align256(off + (size_t)N * 4);
    int* row_start  = (int*)(ws + off); off = align256(off + (size_t)(N + 1) * 4);
    int* cursor     = (int*)(ws + off); off = align256(off + (size_t)N * 4);
    int* bsum       = (int*)(ws + off); off = align256(off + (size_t)nb * 4);
    int* bsum_ex    = (int*)(ws + off); off = align256(off + (size_t)nb * 4);
    int* sorted_src = (int*)(ws + off); off = align256(off + (size_t)E * 4);
    ushort_t* xb    = (ushort_t*)(ws + off); off = align256(off + (size_t)N * IN_F * 2);
    float* h1       = (float*)(ws + off); off = align256(off + (size_t)N * HID * 4);
    ushort_t* ub    = (ushort_t*)(ws + off); off = align256(off + (size_t)N * OUTD * 2);
    float* aggu     = (float*)(ws + off); off = align256(off + (size_t)N * OUTD * 4);
    float* agg1     = (float*)(ws + off);   // N*IN_F*4; reused as h2 afterwards
    float* h2       = agg1;

    hipMemsetAsync(deg_i, 0, (size_t)N * 4, stream);
    init_out_kernel<<<(out_size + 255) / 256, 256, 0, stream>>>(out, out_size);

    // CSR
    hist_kernel<<<(E + 255) / 256, 256, 0, stream>>>(dst, deg_i, E);
    chunk_sum_kernel<<<nb, 256, 0, stream>>>(deg_i, bsum, N);
    scan_bsum_kernel<<<1, 64, 0, stream>>>(bsum, bsum_ex, nb);
    write_rows_kernel<<<nb, 256, 0, stream>>>(deg_i, bsum_ex, row_start, cursor, N, E);
    place_kernel<<<(E + 255) / 256, 256, 0, stream>>>(src, dst, cursor, sorted_src, E);

    // h0 -> bf16
    convert_kernel<<<(N * IN_F + 255) / 256, 256, 0, stream>>>(x, votes, xb, N);

    // layer 1
    gather1_kernel<<<(N + 3) / 4, 256, 0, stream>>>(xb, row_start, sorted_src, agg1, N);
    gemm1_kernel<<<(N + T1_M - 1) / T1_M, 256, 0, stream>>>(x, votes, agg1, W1l, b1, W1r,
                                                            W2l, h1, ub, N);
    // layer 2
    gatheru_kernel<<<(N + 3) / 4, 256, 0, stream>>>(ub, row_start, sorted_src, aggu, N);
    gemm2_kernel<<<(N + 31) / 32, 256, 0, stream>>>(h1, aggu, W2r, b2, h2, N);

    // pool
    segmax_kernel<<<(N + SEG_NODES - 1) / SEG_NODES, 256, 0, stream>>>(h2, batch, out, N);
}